// Round 2
// baseline (19289.500 us; speedup 1.0000x reference)
//
#include <hip/hip_runtime.h>
#include <hip/hip_cooperative_groups.h>

namespace cg = cooperative_groups;

typedef unsigned short u16;
typedef unsigned int u32;
typedef __attribute__((ext_vector_type(8))) short bf16x8;
typedef __attribute__((ext_vector_type(8))) unsigned short u16x8;
typedef __attribute__((ext_vector_type(4))) float f32x4;

// Problem dims: B=128, T=256, D=512, U=1024, G=4U=4096, C=10
// Time axis processed in NCHUNK chunks of TC steps; xz buffer holds one chunk.
#define TC 32
#define NCHUNK 8

static __device__ __forceinline__ u16 f2bf(float x) {
  union { float f; u32 u; } v; v.f = x;
  u32 r = v.u + 0x7fffu + ((v.u >> 16) & 1u);   // round-to-nearest-even
  return (u16)(r >> 16);
}
static __device__ __forceinline__ float bf2f(u16 h) {
  union { u32 u; float f; } v; v.u = ((u32)h) << 16;
  return v.f;
}
static __device__ __forceinline__ float sigm(float x) {
  return 1.0f / (1.0f + __expf(-x));
}
static __device__ __forceinline__ void gload_lds16(const u16* g, u16* l) {
  __builtin_amdgcn_global_load_lds(
      (const __attribute__((address_space(1))) void*)g,
      (__attribute__((address_space(3))) void*)l, 16, 0, 0);
}

// ---------------- prep: x [B,T,D] f32 -> x_hi/x_lo bf16 [T,B,D] ----------------
__global__ __launch_bounds__(256) void conv_x_kernel(const float* __restrict__ x,
                                                     u16* __restrict__ xh,
                                                     u16* __restrict__ xl) {
  int idx = blockIdx.x * 256 + threadIdx.x;      // 2,097,152 threads, 8 elems each
  size_t i8 = (size_t)idx * 8;
  int b = (int)(i8 >> 17);                       // / (256*512)
  int r = (int)(i8 & 131071);
  int t = r >> 9;
  int d = r & 511;
  const f32x4* s = (const f32x4*)(x + i8);
  f32x4 v0 = s[0], v1 = s[1];
  u16x8 vh, vl;
#pragma unroll
  for (int j = 0; j < 8; ++j) {
    float v = (j < 4) ? v0[j] : v1[j - 4];
    u16 h = f2bf(v);
    vh[j] = h;
    vl[j] = f2bf(v - bf2f(h));
  }
  size_t o = ((size_t)(t * 128 + b)) * 512 + d;
  *(u16x8*)(xh + o) = vh;
  *(u16x8*)(xl + o) = vl;
}

// ------------- prep: weight [K,4096] f32 -> [4096,K] bf16 hi/lo (transposed) -------------
__global__ __launch_bounds__(256) void tsplit_kernel(const float* __restrict__ w,
                                                     u16* __restrict__ oh,
                                                     u16* __restrict__ ol, int K) {
  int idx = blockIdx.x * 256 + threadIdx.x;      // K*1024 threads
  int d = idx >> 10;
  int g4 = (idx & 1023) * 4;
  f32x4 v = *(const f32x4*)(w + (size_t)d * 4096 + g4);
#pragma unroll
  for (int j = 0; j < 4; ++j) {
    int g = g4 + j;
    u16 h = f2bf(v[j]);
    oh[(size_t)g * K + d] = h;
    ol[(size_t)g * K + d] = f2bf(v[j] - bf2f(h));
  }
}

// ------------- GEMM1 (per chunk): xz[(t-c*TC)*128+b][g] = x @ kernel + bias -------------
// A = xh/xl rows [c*4096 .. c*4096+4096) of [32768,512]; B = kh/kl [4096,512] ([n][k]);
// C fp32 chunk buffer [4096,4096]. 3-pass split bf16.
__global__ __launch_bounds__(256) void gemm1_kernel(const u16* __restrict__ xh,
                                                    const u16* __restrict__ xl,
                                                    const u16* __restrict__ kh,
                                                    const u16* __restrict__ kl,
                                                    const float* __restrict__ bias,
                                                    float* __restrict__ xz, int c) {
  __shared__ u16 Ah[4096], Al[4096], Bh[4096], Bl[4096];   // 128x32 each, 32KB total
  const int tid = threadIdx.x;
  const int w = tid >> 6, l = tid & 63;
  const int m0w = blockIdx.y * 128;              // row within chunk buffer
  const int m0g = c * 4096 + m0w;                // global A row
  const int n0 = blockIdx.x * 128;
  const int wr = w >> 1, wc = w & 1;
  const int srow = l >> 2, schunk = l & 3;       // staging: lane -> (row, 16B chunk)
  const int fr = l & 15, fc = l >> 4;            // fragment row/col idx, k-chunk

  f32x4 acc[4][4];
#pragma unroll
  for (int a = 0; a < 4; ++a)
#pragma unroll
    for (int b = 0; b < 4; ++b) acc[a][b] = (f32x4){0.f, 0.f, 0.f, 0.f};

  for (int kt = 0; kt < 16; ++kt) {
    const int koff = kt * 32 + schunk * 8;
#pragma unroll
    for (int i = 0; i < 8; ++i) {
      const int q = w + i * 4;                   // 32 staging instrs over 4 waves
      const int buf = q >> 3, ch = q & 7;
      const size_t ro = (size_t)(ch * 16 + srow);
      if (buf == 0)      gload_lds16(xh + (m0g + ro) * 512 + koff, Ah + ch * 512);
      else if (buf == 1) gload_lds16(xl + (m0g + ro) * 512 + koff, Al + ch * 512);
      else if (buf == 2) gload_lds16(kh + (n0 + ro) * 512 + koff, Bh + ch * 512);
      else               gload_lds16(kl + (n0 + ro) * 512 + koff, Bl + ch * 512);
    }
    __syncthreads();

    bf16x8 a_h[4], a_l[4], b_h[4], b_l[4];
#pragma unroll
    for (int mf = 0; mf < 4; ++mf) {
      int row = wr * 64 + mf * 16 + fr;
      a_h[mf] = *(const bf16x8*)(Ah + row * 32 + fc * 8);
      a_l[mf] = *(const bf16x8*)(Al + row * 32 + fc * 8);
    }
#pragma unroll
    for (int nf = 0; nf < 4; ++nf) {
      int col = wc * 64 + nf * 16 + fr;
      b_h[nf] = *(const bf16x8*)(Bh + col * 32 + fc * 8);
      b_l[nf] = *(const bf16x8*)(Bl + col * 32 + fc * 8);
    }
#pragma unroll
    for (int mf = 0; mf < 4; ++mf)
#pragma unroll
      for (int nf = 0; nf < 4; ++nf) {
        acc[mf][nf] = __builtin_amdgcn_mfma_f32_16x16x32_bf16(a_h[mf], b_h[nf], acc[mf][nf], 0, 0, 0);
        acc[mf][nf] = __builtin_amdgcn_mfma_f32_16x16x32_bf16(a_h[mf], b_l[nf], acc[mf][nf], 0, 0, 0);
        acc[mf][nf] = __builtin_amdgcn_mfma_f32_16x16x32_bf16(a_l[mf], b_h[nf], acc[mf][nf], 0, 0, 0);
      }
    __syncthreads();
  }

#pragma unroll
  for (int nf = 0; nf < 4; ++nf) {
    const int col = n0 + wc * 64 + nf * 16 + fr;
    const float bv = bias[col];
#pragma unroll
    for (int mf = 0; mf < 4; ++mf) {
      const int rw = m0w + wr * 64 + mf * 16 + fc * 4;
#pragma unroll
      for (int rg = 0; rg < 4; ++rg)
        xz[(size_t)(rw + rg) * 4096 + col] = acc[mf][nf][rg] + bv;
    }
  }
}

// ------------- cooperative LSTM scan, one chunk of TC steps -------------
// grid = 256 blocks (1/CU). Block: mi = blk>>7 (M-tile of 64 rows), ui = blk&127 (8 U-cols).
// R slice (hi+lo) staged in 128KB LDS in MFMA-fragment order. h ping-pong in global (bf16 hi/lo).
// c-state persists in cf (fp32) across chunk launches.
__global__ __launch_bounds__(256, 1) void lstm_scan_kernel(
    const float* __restrict__ xz,
    const u16* __restrict__ rwh, const u16* __restrict__ rwl,
    u16* __restrict__ hh, u16* __restrict__ hl,
    float* __restrict__ cf, int c) {
  __shared__ u16 Rh[32768];   // [nf 2][ks 32][lane 64][8]  = 64KB
  __shared__ u16 Rl[32768];   // 64KB
  const int tid = threadIdx.x;
  const int w = tid >> 6, l = tid & 63;
  const int blk = blockIdx.x;
  const int mi = blk >> 7, ui = blk & 127;

  // stage R fragments: frag layout so compute does contiguous 16B ds_reads
  for (int gidx = tid; gidx < 4096; gidx += 256) {
    const int lr = gidx & 63;
    const int ks = (gidx >> 6) & 31;
    const int nf = gidx >> 11;
    const int cc = lr & 15;
    const int kb = ks * 32 + ((lr >> 4) << 3);
    const int gate = nf * 2 + (cc >> 3);
    const size_t gcol = (size_t)(gate * 1024 + ui * 8 + (cc & 7));
    *(u16x8*)(Rh + gidx * 8) = *(const u16x8*)(rwh + gcol * 1024 + kb);
    *(u16x8*)(Rl + gidx * 8) = *(const u16x8*)(rwl + gcol * 1024 + kb);
  }
  __syncthreads();

  cg::grid_group grid = cg::this_grid();

  const int fr = l & 15, fc = l >> 4;
  const int arow = mi * 64 + w * 16 + fr;        // A-fragment row (batch index)
  const int crow = mi * 64 + w * 16 + fc * 4;    // C rows base (batch index)
  const int uu = ui * 8 + (fr & 7);
  const int gcol0 = ((fr >> 3) ? 1024 : 0) + uu;      // i or f column
  const int gcol1 = ((fr >> 3) ? 3072 : 2048) + uu;   // g or o column
  float cs[4] = {0.f, 0.f, 0.f, 0.f};
  if (c && fr < 8) {
#pragma unroll
    for (int rg = 0; rg < 4; ++rg) cs[rg] = cf[(size_t)(crow + rg) * 1024 + uu];
  }

  for (int tc = 0; tc < TC; ++tc) {
    f32x4 a0 = (f32x4){0.f, 0.f, 0.f, 0.f};
    f32x4 a1 = (f32x4){0.f, 0.f, 0.f, 0.f};
    if (c || tc) {   // global t=0: h=0, z = xz only
      const u16* ph = hh + ((size_t)(tc & 1) << 17) + (size_t)arow * 1024 + fc * 8;
      const u16* pl = hl + ((size_t)(tc & 1) << 17) + (size_t)arow * 1024 + fc * 8;
#pragma unroll 4
      for (int ks = 0; ks < 32; ++ks) {
        bf16x8 avh = *(const bf16x8*)(ph + ks * 32);
        bf16x8 avl = *(const bf16x8*)(pl + ks * 32);
        bf16x8 b0h = *(const bf16x8*)(Rh + (ks * 64 + l) * 8);
        bf16x8 b0l = *(const bf16x8*)(Rl + (ks * 64 + l) * 8);
        bf16x8 b1h = *(const bf16x8*)(Rh + ((32 + ks) * 64 + l) * 8);
        bf16x8 b1l = *(const bf16x8*)(Rl + ((32 + ks) * 64 + l) * 8);
        a0 = __builtin_amdgcn_mfma_f32_16x16x32_bf16(avh, b0h, a0, 0, 0, 0);
        a0 = __builtin_amdgcn_mfma_f32_16x16x32_bf16(avh, b0l, a0, 0, 0, 0);
        a0 = __builtin_amdgcn_mfma_f32_16x16x32_bf16(avl, b0h, a0, 0, 0, 0);
        a1 = __builtin_amdgcn_mfma_f32_16x16x32_bf16(avh, b1h, a1, 0, 0, 0);
        a1 = __builtin_amdgcn_mfma_f32_16x16x32_bf16(avh, b1l, a1, 0, 0, 0);
        a1 = __builtin_amdgcn_mfma_f32_16x16x32_bf16(avl, b1h, a1, 0, 0, 0);
      }
    }
    const float* xzt = xz + ((size_t)tc << 19);  // tc * 128 * 4096
    float z0[4], z1[4];
#pragma unroll
    for (int rg = 0; rg < 4; ++rg) {
      z0[rg] = a0[rg] + xzt[(size_t)(crow + rg) * 4096 + gcol0];
      z1[rg] = a1[rg] + xzt[(size_t)(crow + rg) * 4096 + gcol1];
    }
    u16* wh = hh + ((size_t)((tc + 1) & 1) << 17);
    u16* wl = hl + ((size_t)((tc + 1) & 1) << 17);
#pragma unroll
    for (int rg = 0; rg < 4; ++rg) {
      float p0 = __shfl_xor(z0[rg], 8, 64);      // pair (i,f) / (g,o) lanes
      float p1 = __shfl_xor(z1[rg], 8, 64);
      if (fr < 8) {
        float ig = sigm(z0[rg]);
        float fg = sigm(p0);
        float gg = tanhf(z1[rg]);
        float og = sigm(p1);
        float cn = fg * cs[rg] + ig * gg;
        cs[rg] = cn;
        float hv = og * tanhf(cn);
        u16 hi = f2bf(hv);
        u16 lo = f2bf(hv - bf2f(hi));
        wh[(size_t)(crow + rg) * 1024 + uu] = hi;
        wl[(size_t)(crow + rg) * 1024 + uu] = lo;
      }
    }
    __threadfence();
    grid.sync();
  }

  if (fr < 8) {
#pragma unroll
    for (int rg = 0; rg < 4; ++rg) cf[(size_t)(crow + rg) * 1024 + uu] = cs[rg];
  }
}

// ------------- classifier + softmax: one block per batch row -------------
__global__ __launch_bounds__(256) void cls_kernel(const u16* __restrict__ hh,
                                                  const u16* __restrict__ hl,
                                                  const float* __restrict__ wcls,
                                                  const float* __restrict__ bcls,
                                                  float* __restrict__ out) {
  __shared__ float red[2560];
  const int tid = threadIdx.x;
  const int row = blockIdx.x;
  float acc[10];
#pragma unroll
  for (int cc = 0; cc < 10; ++cc) acc[cc] = 0.f;
  const u16* hr = hh + (size_t)row * 1024;       // h_last lives in buffer 0
  const u16* hrl = hl + (size_t)row * 1024;
  const int k0 = tid * 4;
  for (int k = k0; k < k0 + 4; ++k) {
    float hv = bf2f(hr[k]) + bf2f(hrl[k]);
#pragma unroll
    for (int cc = 0; cc < 10; ++cc) acc[cc] += hv * wcls[(size_t)k * 10 + cc];
  }
#pragma unroll
  for (int cc = 0; cc < 10; ++cc) red[tid * 10 + cc] = acc[cc];
  __syncthreads();
  for (int s = 128; s >= 1; s >>= 1) {
    if (tid < s) {
#pragma unroll
      for (int cc = 0; cc < 10; ++cc) red[tid * 10 + cc] += red[(tid + s) * 10 + cc];
    }
    __syncthreads();
  }
  if (tid == 0) {
    float lg[10];
    float m = -1e30f;
#pragma unroll
    for (int cc = 0; cc < 10; ++cc) { lg[cc] = red[cc] + bcls[cc]; m = fmaxf(m, lg[cc]); }
    float ssum = 0.f;
#pragma unroll
    for (int cc = 0; cc < 10; ++cc) { lg[cc] = __expf(lg[cc] - m); ssum += lg[cc]; }
    float inv = 1.f / ssum;
#pragma unroll
    for (int cc = 0; cc < 10; ++cc) out[row * 10 + cc] = lg[cc] * inv;
  }
}

// ---------------- host ----------------
extern "C" void kernel_launch(void* const* d_in, const int* in_sizes, int n_in,
                              void* d_out, int out_size, void* d_ws, size_t ws_size,
                              hipStream_t stream) {
  const float* x    = (const float*)d_in[0];
  const float* kern = (const float*)d_in[1];
  const float* rker = (const float*)d_in[2];
  const float* bias = (const float*)d_in[3];
  const float* wcls = (const float*)d_in[4];
  const float* bcls = (const float*)d_in[5];
  float* out = (float*)d_out;
  char* ws = (char*)d_ws;

  // workspace layout (bytes) — total 160,956,416 (~153.5 MB)
  float* xz = (float*)(ws + 0UL);                 //  67,108,864  xz chunk fp32 [TC][128][4096]
  u16* xh   = (u16*)(ws + 67108864UL);            //  33,554,432  x hi bf16 [T*128][512]
  u16* xl   = (u16*)(ws + 100663296UL);           //  33,554,432
  u16* kh   = (u16*)(ws + 134217728UL);           //   4,194,304  kernel^T hi [4096][512]
  u16* kl   = (u16*)(ws + 138412032UL);           //   4,194,304
  u16* rh   = (u16*)(ws + 142606336UL);           //   8,388,608  R^T hi [4096][1024]
  u16* rl   = (u16*)(ws + 150994944UL);           //   8,388,608
  u16* hh   = (u16*)(ws + 159383552UL);           //     524,288  h hi ping-pong [2][128][1024]
  u16* hl   = (u16*)(ws + 159907840UL);           //     524,288
  float* cf = (float*)(ws + 160432128UL);         //     524,288  c state fp32 [128][1024]

  conv_x_kernel<<<8192, 256, 0, stream>>>(x, xh, xl);
  tsplit_kernel<<<2048, 256, 0, stream>>>(kern, kh, kl, 512);
  tsplit_kernel<<<4096, 256, 0, stream>>>(rker, rh, rl, 1024);

  int cvals[NCHUNK];
  for (int c = 0; c < NCHUNK; ++c) cvals[c] = c;
  for (int c = 0; c < NCHUNK; ++c) {
    gemm1_kernel<<<dim3(32, 32), 256, 0, stream>>>(xh, xl, kh, kl, bias, xz, c);
    void* sargs[7];
    sargs[0] = (void*)&xz;
    sargs[1] = (void*)&rh;
    sargs[2] = (void*)&rl;
    sargs[3] = (void*)&hh;
    sargs[4] = (void*)&hl;
    sargs[5] = (void*)&cf;
    sargs[6] = (void*)&cvals[c];
    hipLaunchCooperativeKernel((const void*)lstm_scan_kernel, dim3(256), dim3(256),
                               sargs, 0u, stream);
  }
  cls_kernel<<<128, 256, 0, stream>>>(hh, hl, wcls, bcls, out);
}

// Round 3
// 5572.781 us; speedup vs baseline: 3.4614x; 3.4614x over previous
//
#include <hip/hip_runtime.h>

typedef unsigned short u16;
typedef unsigned int u32;
typedef __attribute__((ext_vector_type(8))) short bf16x8;
typedef __attribute__((ext_vector_type(8))) unsigned short u16x8;
typedef __attribute__((ext_vector_type(4))) float f32x4;

// Problem dims: B=128, T=256, D=512, U=1024, G=4U=4096, C=10
// Time axis processed in NCHUNK chunks of TC steps; xz buffer holds one chunk.
#define TC 32
#define NCHUNK 8

static __device__ __forceinline__ u16 f2bf(float x) {
  union { float f; u32 u; } v; v.f = x;
  u32 r = v.u + 0x7fffu + ((v.u >> 16) & 1u);   // round-to-nearest-even
  return (u16)(r >> 16);
}
static __device__ __forceinline__ float bf2f(u16 h) {
  union { u32 u; float f; } v; v.u = ((u32)h) << 16;
  return v.f;
}
static __device__ __forceinline__ float sigm(float x) {
  return 1.0f / (1.0f + __expf(-x));
}
static __device__ __forceinline__ void gload_lds16(const u16* g, u16* l) {
  __builtin_amdgcn_global_load_lds(
      (const __attribute__((address_space(1))) void*)g,
      (__attribute__((address_space(3))) void*)l, 16, 0, 0);
}

// ---------------- prep: x [B,T,D] f32 -> x_hi/x_lo bf16 [T,B,D] ----------------
__global__ __launch_bounds__(256) void conv_x_kernel(const float* __restrict__ x,
                                                     u16* __restrict__ xh,
                                                     u16* __restrict__ xl) {
  int idx = blockIdx.x * 256 + threadIdx.x;      // 1,048,576 threads? no: 2,097,152 elems/8
  size_t i8 = (size_t)idx * 8;
  int b = (int)(i8 >> 17);                       // / (256*512)
  int r = (int)(i8 & 131071);
  int t = r >> 9;
  int d = r & 511;
  const f32x4* s = (const f32x4*)(x + i8);
  f32x4 v0 = s[0], v1 = s[1];
  u16x8 vh, vl;
#pragma unroll
  for (int j = 0; j < 8; ++j) {
    float v = (j < 4) ? v0[j] : v1[j - 4];
    u16 h = f2bf(v);
    vh[j] = h;
    vl[j] = f2bf(v - bf2f(h));
  }
  size_t o = ((size_t)(t * 128 + b)) * 512 + d;
  *(u16x8*)(xh + o) = vh;
  *(u16x8*)(xl + o) = vl;
}

// ------------- prep: weight [K,4096] f32 -> [4096,K] bf16 hi/lo (transposed) -------------
__global__ __launch_bounds__(256) void tsplit_kernel(const float* __restrict__ w,
                                                     u16* __restrict__ oh,
                                                     u16* __restrict__ ol, int K) {
  int idx = blockIdx.x * 256 + threadIdx.x;      // K*1024 threads
  int d = idx >> 10;
  int g4 = (idx & 1023) * 4;
  f32x4 v = *(const f32x4*)(w + (size_t)d * 4096 + g4);
#pragma unroll
  for (int j = 0; j < 4; ++j) {
    int g = g4 + j;
    u16 h = f2bf(v[j]);
    oh[(size_t)g * K + d] = h;
    ol[(size_t)g * K + d] = f2bf(v[j] - bf2f(h));
  }
}

// ------------- GEMM1 (per chunk): xz[(t-c*TC)*128+b][g] = x @ kernel + bias -------------
__global__ __launch_bounds__(256) void gemm1_kernel(const u16* __restrict__ xh,
                                                    const u16* __restrict__ xl,
                                                    const u16* __restrict__ kh,
                                                    const u16* __restrict__ kl,
                                                    const float* __restrict__ bias,
                                                    float* __restrict__ xz, int c) {
  __shared__ u16 Ah[4096], Al[4096], Bh[4096], Bl[4096];   // 128x32 each, 32KB total
  const int tid = threadIdx.x;
  const int w = tid >> 6, l = tid & 63;
  const int m0w = blockIdx.y * 128;              // row within chunk buffer
  const int m0g = c * 4096 + m0w;                // global A row
  const int n0 = blockIdx.x * 128;
  const int wr = w >> 1, wc = w & 1;
  const int srow = l >> 2, schunk = l & 3;       // staging: lane -> (row, 16B chunk)
  const int fr = l & 15, fc = l >> 4;            // fragment row/col idx, k-chunk

  f32x4 acc[4][4];
#pragma unroll
  for (int a = 0; a < 4; ++a)
#pragma unroll
    for (int b = 0; b < 4; ++b) acc[a][b] = (f32x4){0.f, 0.f, 0.f, 0.f};

  for (int kt = 0; kt < 16; ++kt) {
    const int koff = kt * 32 + schunk * 8;
#pragma unroll
    for (int i = 0; i < 8; ++i) {
      const int q = w + i * 4;                   // 32 staging instrs over 4 waves
      const int buf = q >> 3, ch = q & 7;
      const size_t ro = (size_t)(ch * 16 + srow);
      if (buf == 0)      gload_lds16(xh + (m0g + ro) * 512 + koff, Ah + ch * 512);
      else if (buf == 1) gload_lds16(xl + (m0g + ro) * 512 + koff, Al + ch * 512);
      else if (buf == 2) gload_lds16(kh + (n0 + ro) * 512 + koff, Bh + ch * 512);
      else               gload_lds16(kl + (n0 + ro) * 512 + koff, Bl + ch * 512);
    }
    __syncthreads();

    bf16x8 a_h[4], a_l[4], b_h[4], b_l[4];
#pragma unroll
    for (int mf = 0; mf < 4; ++mf) {
      int row = wr * 64 + mf * 16 + fr;
      a_h[mf] = *(const bf16x8*)(Ah + row * 32 + fc * 8);
      a_l[mf] = *(const bf16x8*)(Al + row * 32 + fc * 8);
    }
#pragma unroll
    for (int nf = 0; nf < 4; ++nf) {
      int col = wc * 64 + nf * 16 + fr;
      b_h[nf] = *(const bf16x8*)(Bh + col * 32 + fc * 8);
      b_l[nf] = *(const bf16x8*)(Bl + col * 32 + fc * 8);
    }
#pragma unroll
    for (int mf = 0; mf < 4; ++mf)
#pragma unroll
      for (int nf = 0; nf < 4; ++nf) {
        acc[mf][nf] = __builtin_amdgcn_mfma_f32_16x16x32_bf16(a_h[mf], b_h[nf], acc[mf][nf], 0, 0, 0);
        acc[mf][nf] = __builtin_amdgcn_mfma_f32_16x16x32_bf16(a_h[mf], b_l[nf], acc[mf][nf], 0, 0, 0);
        acc[mf][nf] = __builtin_amdgcn_mfma_f32_16x16x32_bf16(a_l[mf], b_h[nf], acc[mf][nf], 0, 0, 0);
      }
    __syncthreads();
  }

#pragma unroll
  for (int nf = 0; nf < 4; ++nf) {
    const int col = n0 + wc * 64 + nf * 16 + fr;
    const float bv = bias[col];
#pragma unroll
    for (int mf = 0; mf < 4; ++mf) {
      const int rw = m0w + wr * 64 + mf * 16 + fc * 4;
#pragma unroll
      for (int rg = 0; rg < 4; ++rg)
        xz[(size_t)(rw + rg) * 4096 + col] = acc[mf][nf][rg] + bv;
    }
  }
}

// ------------- LSTM single step: one launch per timestep (kernel boundary = barrier) -------------
// grid = 256 blocks. Block: mi = blk>>7 (64 batch rows), ui = blk&127 (8 U-cols).
// R slice (hi+lo) staged into 128KB LDS via global_load_lds each launch.
// h ping-pong in global bf16 hi/lo; c-state in global fp32.
__global__ __launch_bounds__(256, 1) void lstm_step_kernel(
    const float* __restrict__ xz,
    const u16* __restrict__ rwh, const u16* __restrict__ rwl,
    u16* __restrict__ hh, u16* __restrict__ hl,
    float* __restrict__ cf, int t, int tc) {
  __shared__ u16 Rh[32768];   // [nf 2][ks 32][lane 64][8]  = 64KB
  __shared__ u16 Rl[32768];   // 64KB
  const int tid = threadIdx.x;
  const int w = tid >> 6, l = tid & 63;
  const int blk = blockIdx.x;
  const int mi = blk >> 7, ui = blk & 127;

  // stage R fragments via global_load_lds: dest = wave-uniform base + lane*16B
#pragma unroll
  for (int it = 0; it < 16; ++it) {
    const int gidx = it * 256 + tid;
    const int lr = gidx & 63;
    const int ks = (gidx >> 6) & 31;
    const int nf = gidx >> 11;
    const int cc = lr & 15;
    const int kb = ks * 32 + ((lr >> 4) << 3);
    const int gate = nf * 2 + (cc >> 3);
    const size_t gcol = (size_t)(gate * 1024 + ui * 8 + (cc & 7));
    gload_lds16(rwh + gcol * 1024 + kb, Rh + gidx * 8);
    gload_lds16(rwl + gcol * 1024 + kb, Rl + gidx * 8);
  }

  const int fr = l & 15, fc = l >> 4;
  const int arow = mi * 64 + w * 16 + fr;        // A-fragment row (batch index)
  const int crow = mi * 64 + w * 16 + fc * 4;    // C rows base (batch index)
  const int uu = ui * 8 + (fr & 7);
  const int gcol0 = ((fr >> 3) ? 1024 : 0) + uu;      // i or f column
  const int gcol1 = ((fr >> 3) ? 3072 : 2048) + uu;   // g or o column

  float cs[4] = {0.f, 0.f, 0.f, 0.f};
  if (t && fr < 8) {
#pragma unroll
    for (int rg = 0; rg < 4; ++rg) cs[rg] = cf[(size_t)(crow + rg) * 1024 + uu];
  }

  __syncthreads();   // drains global_load_lds (vmcnt) + barrier

  f32x4 a0 = (f32x4){0.f, 0.f, 0.f, 0.f};
  f32x4 a1 = (f32x4){0.f, 0.f, 0.f, 0.f};
  if (t) {   // t=0: h=0, z = xz only
    const u16* ph = hh + ((size_t)(t & 1) << 17) + (size_t)arow * 1024 + fc * 8;
    const u16* pl = hl + ((size_t)(t & 1) << 17) + (size_t)arow * 1024 + fc * 8;
#pragma unroll 4
    for (int ks = 0; ks < 32; ++ks) {
      bf16x8 avh = *(const bf16x8*)(ph + ks * 32);
      bf16x8 avl = *(const bf16x8*)(pl + ks * 32);
      bf16x8 b0h = *(const bf16x8*)(Rh + (ks * 64 + l) * 8);
      bf16x8 b0l = *(const bf16x8*)(Rl + (ks * 64 + l) * 8);
      bf16x8 b1h = *(const bf16x8*)(Rh + ((32 + ks) * 64 + l) * 8);
      bf16x8 b1l = *(const bf16x8*)(Rl + ((32 + ks) * 64 + l) * 8);
      a0 = __builtin_amdgcn_mfma_f32_16x16x32_bf16(avh, b0h, a0, 0, 0, 0);
      a0 = __builtin_amdgcn_mfma_f32_16x16x32_bf16(avh, b0l, a0, 0, 0, 0);
      a0 = __builtin_amdgcn_mfma_f32_16x16x32_bf16(avl, b0h, a0, 0, 0, 0);
      a1 = __builtin_amdgcn_mfma_f32_16x16x32_bf16(avh, b1h, a1, 0, 0, 0);
      a1 = __builtin_amdgcn_mfma_f32_16x16x32_bf16(avh, b1l, a1, 0, 0, 0);
      a1 = __builtin_amdgcn_mfma_f32_16x16x32_bf16(avl, b1h, a1, 0, 0, 0);
    }
  }
  const float* xzt = xz + ((size_t)tc << 19);    // tc * 128 * 4096
  float z0[4], z1[4];
#pragma unroll
  for (int rg = 0; rg < 4; ++rg) {
    z0[rg] = a0[rg] + xzt[(size_t)(crow + rg) * 4096 + gcol0];
    z1[rg] = a1[rg] + xzt[(size_t)(crow + rg) * 4096 + gcol1];
  }
  u16* wh = hh + ((size_t)((t + 1) & 1) << 17);
  u16* wl = hl + ((size_t)((t + 1) & 1) << 17);
#pragma unroll
  for (int rg = 0; rg < 4; ++rg) {
    float p0 = __shfl_xor(z0[rg], 8, 64);        // pair (i,f) / (g,o) lanes
    float p1 = __shfl_xor(z1[rg], 8, 64);
    if (fr < 8) {
      float ig = sigm(z0[rg]);
      float fg = sigm(p0);
      float gg = tanhf(z1[rg]);
      float og = sigm(p1);
      float cn = fg * cs[rg] + ig * gg;
      cs[rg] = cn;
      float hv = og * tanhf(cn);
      u16 hi = f2bf(hv);
      u16 lo = f2bf(hv - bf2f(hi));
      wh[(size_t)(crow + rg) * 1024 + uu] = hi;
      wl[(size_t)(crow + rg) * 1024 + uu] = lo;
    }
  }
  if (fr < 8) {
#pragma unroll
    for (int rg = 0; rg < 4; ++rg) cf[(size_t)(crow + rg) * 1024 + uu] = cs[rg];
  }
}

// ------------- classifier + softmax: one block per batch row -------------
__global__ __launch_bounds__(256) void cls_kernel(const u16* __restrict__ hh,
                                                  const u16* __restrict__ hl,
                                                  const float* __restrict__ wcls,
                                                  const float* __restrict__ bcls,
                                                  float* __restrict__ out) {
  __shared__ float red[2560];
  const int tid = threadIdx.x;
  const int row = blockIdx.x;
  float acc[10];
#pragma unroll
  for (int cc = 0; cc < 10; ++cc) acc[cc] = 0.f;
  const u16* hr = hh + (size_t)row * 1024;       // h_last lives in buffer 0 (t=255 writes buf 0)
  const u16* hrl = hl + (size_t)row * 1024;
  const int k0 = tid * 4;
  for (int k = k0; k < k0 + 4; ++k) {
    float hv = bf2f(hr[k]) + bf2f(hrl[k]);
#pragma unroll
    for (int cc = 0; cc < 10; ++cc) acc[cc] += hv * wcls[(size_t)k * 10 + cc];
  }
#pragma unroll
  for (int cc = 0; cc < 10; ++cc) red[tid * 10 + cc] = acc[cc];
  __syncthreads();
  for (int s = 128; s >= 1; s >>= 1) {
    if (tid < s) {
#pragma unroll
      for (int cc = 0; cc < 10; ++cc) red[tid * 10 + cc] += red[(tid + s) * 10 + cc];
    }
    __syncthreads();
  }
  if (tid == 0) {
    float lg[10];
    float m = -1e30f;
#pragma unroll
    for (int cc = 0; cc < 10; ++cc) { lg[cc] = red[cc] + bcls[cc]; m = fmaxf(m, lg[cc]); }
    float ssum = 0.f;
#pragma unroll
    for (int cc = 0; cc < 10; ++cc) { lg[cc] = __expf(lg[cc] - m); ssum += lg[cc]; }
    float inv = 1.f / ssum;
#pragma unroll
    for (int cc = 0; cc < 10; ++cc) out[row * 10 + cc] = lg[cc] * inv;
  }
}

// ---------------- host ----------------
extern "C" void kernel_launch(void* const* d_in, const int* in_sizes, int n_in,
                              void* d_out, int out_size, void* d_ws, size_t ws_size,
                              hipStream_t stream) {
  const float* x    = (const float*)d_in[0];
  const float* kern = (const float*)d_in[1];
  const float* rker = (const float*)d_in[2];
  const float* bias = (const float*)d_in[3];
  const float* wcls = (const float*)d_in[4];
  const float* bcls = (const float*)d_in[5];
  float* out = (float*)d_out;
  char* ws = (char*)d_ws;

  // workspace layout (bytes) — total 160,956,416 (~153.5 MB)
  float* xz = (float*)(ws + 0UL);                 //  67,108,864  xz chunk fp32 [TC][128][4096]
  u16* xh   = (u16*)(ws + 67108864UL);            //  33,554,432  x hi bf16 [T*128][512]
  u16* xl   = (u16*)(ws + 100663296UL);           //  33,554,432
  u16* kh   = (u16*)(ws + 134217728UL);           //   4,194,304  kernel^T hi [4096][512]
  u16* kl   = (u16*)(ws + 138412032UL);           //   4,194,304
  u16* rh   = (u16*)(ws + 142606336UL);           //   8,388,608  R^T hi [4096][1024]
  u16* rl   = (u16*)(ws + 150994944UL);           //   8,388,608
  u16* hh   = (u16*)(ws + 159383552UL);           //     524,288  h hi ping-pong [2][128][1024]
  u16* hl   = (u16*)(ws + 159907840UL);           //     524,288
  float* cf = (float*)(ws + 160432128UL);         //     524,288  c state fp32 [128][1024]

  conv_x_kernel<<<8192, 256, 0, stream>>>(x, xh, xl);
  tsplit_kernel<<<2048, 256, 0, stream>>>(kern, kh, kl, 512);
  tsplit_kernel<<<4096, 256, 0, stream>>>(rker, rh, rl, 1024);

  for (int c = 0; c < NCHUNK; ++c) {
    gemm1_kernel<<<dim3(32, 32), 256, 0, stream>>>(xh, xl, kh, kl, bias, xz, c);
    for (int tc = 0; tc < TC; ++tc) {
      lstm_step_kernel<<<256, 256, 0, stream>>>(xz, rh, rl, hh, hl, cf,
                                                c * TC + tc, tc);
    }
  }
  cls_kernel<<<128, 256, 0, stream>>>(hh, hl, wcls, bcls, out);
}